// Round 12
// baseline (436.837 us; speedup 1.0000x reference)
//
#include <hip/hip_runtime.h>
#include <hip/hip_bf16.h>
#include <math.h>
#include <stdint.h>

typedef short short8 __attribute__((ext_vector_type(8)));
typedef float f32x4 __attribute__((ext_vector_type(4)));

__device__ __forceinline__ float bf2f(unsigned int u) {
    union { unsigned int i; float f; } x; x.i = u << 16; return x.f;
}
__device__ __forceinline__ unsigned short f2bf(float f) {
    union { float f; unsigned int i; } x; x.f = f;
    unsigned int r = x.i + 0x7fffu + ((x.i >> 16) & 1u);
    return (unsigned short)(r >> 16);
}

// ---------------- CSR build ----------------
__global__ void block_sums(const int* __restrict__ deg, int* __restrict__ bs, int N) {
    __shared__ int tmp[256];
    int t = threadIdx.x;
    int i = blockIdx.x * 256 + t;
    tmp[t] = (i < N) ? deg[i] : 0;
    __syncthreads();
    for (int off = 128; off > 0; off >>= 1) {
        if (t < off) tmp[t] += tmp[t + off];
        __syncthreads();
    }
    if (t == 0) bs[blockIdx.x] = tmp[0];
}
__global__ void scan_bs(const int* __restrict__ bs, int* __restrict__ bo, int B) {
    __shared__ int tmp[256];
    int t = threadIdx.x;
    int v = (t < B) ? bs[t] : 0;
    tmp[t] = v;
    __syncthreads();
    for (int off = 1; off < 256; off <<= 1) {
        int x = (t >= off) ? tmp[t - off] : 0;
        __syncthreads();
        tmp[t] += x;
        __syncthreads();
    }
    bo[t] = tmp[t] - v;
}
__global__ void finalize_rowptr(const int* __restrict__ deg, const int* __restrict__ bo,
                                int* __restrict__ rowptr, int* __restrict__ cursor,
                                int N, int E) {
    __shared__ int tmp[256];
    int t = threadIdx.x;
    int i = blockIdx.x * 256 + t;
    int v = (i < N) ? deg[i] : 0;
    tmp[t] = v;
    __syncthreads();
    for (int off = 1; off < 256; off <<= 1) {
        int x = (t >= off) ? tmp[t - off] : 0;
        __syncthreads();
        tmp[t] += x;
        __syncthreads();
    }
    int excl = tmp[t] - v + bo[blockIdx.x];
    if (i < N) { rowptr[i] = excl; cursor[i] = excl; }
    if (i == N) rowptr[N] = E;
}
__global__ void fill_csr(const int* __restrict__ row, const int* __restrict__ col,
                         int* __restrict__ cursor, int* __restrict__ idx, int E) {
    int e = blockIdx.x * blockDim.x + threadIdx.x;
    if (e < E) {
        int p = atomicAdd(&cursor[row[e]], 1);
        idx[p] = col[e];
    }
}

// ---------------- merged zero + prep ----------------
__global__ void zero_all(int* __restrict__ deg, int n_deg,
                         uint4* __restrict__ a, uint4* __restrict__ b, uint4* __restrict__ c,
                         int n_t, uint4* __restrict__ st, int n_st) {
    int i = blockIdx.x * blockDim.x + threadIdx.x;
    uint4 z = make_uint4(0, 0, 0, 0);
    if (i < n_deg) deg[i] = 0;
    if (i < n_t) { a[i] = z; b[i] = z; c[i] = z; }
    if (i < n_st) st[i] = z;
}

// conv_x (nconv float4-items) + weight transpose/convert (360448) + degree hist (E)
__global__ void prep_all(const float* __restrict__ x, unsigned short* __restrict__ xb, int nconv,
                         const float* __restrict__ W1_0, const float* __restrict__ W1rest,
                         const float* __restrict__ W2, unsigned short* __restrict__ wt,
                         const int* __restrict__ erow, int* __restrict__ deg, int E) {
    int i = blockIdx.x * blockDim.x + threadIdx.x;
    if (i < nconv) {
        float4 v = *(const float4*)(x + (size_t)i * 4);
        unsigned int lo = (unsigned int)f2bf(v.x) | ((unsigned int)f2bf(v.y) << 16);
        unsigned int hi = (unsigned int)f2bf(v.z) | ((unsigned int)f2bf(v.w) << 16);
        *(uint2*)(xb + (size_t)i * 4) = make_uint2(lo, hi);
        return;
    }
    int id = i - nconv;
    if (id < 32768) {                       // W1_0 [128][256] -> [256][128]
        int k = id >> 8, c = id & 255;
        wt[c * 128 + k] = f2bf(W1_0[id]);
        return;
    } else if (id < 163840) {               // W1rest 2x [256][256]
        int t = id - 32768;
        int m = t >> 16, r = t & 65535;
        int k = r >> 8, c = r & 255;
        wt[32768 + m * 65536 + c * 256 + k] = f2bf(W1rest[t]);
        return;
    } else if (id < 360448) {               // W2 3x [256][256]
        int t = id - 163840;
        int m = t >> 16, r = t & 65535;
        int k = r >> 8, c = r & 255;
        wt[163840 + m * 65536 + c * 256 + k] = f2bf(W2[t]);
        return;
    }
    int e = id - 360448;
    if (e < E) atomicAdd(&deg[erow[e]], 1);
}

// ---------------- pull aggregation (R5-proven) + optional fused BN+ReLU -----
// out[v] = (1+eps)*T(h[v]) + sum_{u in N(v)} T(h[u]);  T = id or relu(x*sc+sh),
// sc/sh computed per-lane from column stats. One wave per node, 4-edge unroll.
template<int H, bool FUSE_BN>
__global__ __launch_bounds__(256) void aggregate_f(
    const unsigned short* __restrict__ h,
    const int* __restrict__ rowptr, const int* __restrict__ idx,
    const float* __restrict__ eps_p, int layer,
    const float* __restrict__ stats, const float* __restrict__ g,
    const float* __restrict__ bt, float invN,
    unsigned short* __restrict__ out, int N) {
    constexpr int NW = H / 128;  // uints (bf16 pairs) per lane
    int lane = threadIdx.x & 63;
    int v = blockIdx.x * 4 + (threadIdx.x >> 6);
    if (v >= N) return;

    float sc[2 * NW], sh[2 * NW];
    if constexpr (FUSE_BN) {
#pragma unroll
        for (int j = 0; j < 2 * NW; ++j) {
            int c = lane * 2 * NW + j;
            float m = stats[c] * invN;
            float var = stats[256 + c] * invN - m * m;
            sc[j] = g[c] * rsqrtf(var + 1e-5f);
            sh[j] = bt[c] - m * sc[j];
        }
    }
    const float s = 1.f + eps_p[layer];
    const unsigned int* hu = (const unsigned int*)h;

    float acc[2 * NW];
    {
        const unsigned int* hv = hu + (size_t)v * (H / 2) + lane * NW;
#pragma unroll
        for (int j = 0; j < NW; ++j) {
            unsigned int r = hv[j];
            float f0 = bf2f(r & 0xffffu), f1 = bf2f(r >> 16);
            if constexpr (FUSE_BN) {
                f0 = fmaxf(f0 * sc[2 * j] + sh[2 * j], 0.f);
                f1 = fmaxf(f1 * sc[2 * j + 1] + sh[2 * j + 1], 0.f);
            }
            acc[2 * j] = s * f0;
            acc[2 * j + 1] = s * f1;
        }
    }
    int e = rowptr[v], end = rowptr[v + 1];
    for (; e + 3 < end; e += 4) {
        int u0 = idx[e], u1 = idx[e + 1], u2 = idx[e + 2], u3 = idx[e + 3];
        const unsigned int* q0 = hu + (size_t)u0 * (H / 2) + lane * NW;
        const unsigned int* q1 = hu + (size_t)u1 * (H / 2) + lane * NW;
        const unsigned int* q2 = hu + (size_t)u2 * (H / 2) + lane * NW;
        const unsigned int* q3 = hu + (size_t)u3 * (H / 2) + lane * NW;
        unsigned int r0[NW], r1[NW], r2[NW], r3[NW];
#pragma unroll
        for (int j = 0; j < NW; ++j) { r0[j] = q0[j]; r1[j] = q1[j]; r2[j] = q2[j]; r3[j] = q3[j]; }
#pragma unroll
        for (int j = 0; j < NW; ++j) {
            float a0 = bf2f(r0[j] & 0xffffu), b0 = bf2f(r0[j] >> 16);
            float a1 = bf2f(r1[j] & 0xffffu), b1 = bf2f(r1[j] >> 16);
            float a2 = bf2f(r2[j] & 0xffffu), b2 = bf2f(r2[j] >> 16);
            float a3 = bf2f(r3[j] & 0xffffu), b3 = bf2f(r3[j] >> 16);
            if constexpr (FUSE_BN) {
                float c0 = sc[2 * j], d0 = sh[2 * j], c1 = sc[2 * j + 1], d1 = sh[2 * j + 1];
                a0 = fmaxf(a0 * c0 + d0, 0.f); b0 = fmaxf(b0 * c1 + d1, 0.f);
                a1 = fmaxf(a1 * c0 + d0, 0.f); b1 = fmaxf(b1 * c1 + d1, 0.f);
                a2 = fmaxf(a2 * c0 + d0, 0.f); b2 = fmaxf(b2 * c1 + d1, 0.f);
                a3 = fmaxf(a3 * c0 + d0, 0.f); b3 = fmaxf(b3 * c1 + d1, 0.f);
            }
            acc[2 * j]     += (a0 + a1) + (a2 + a3);
            acc[2 * j + 1] += (b0 + b1) + (b2 + b3);
        }
    }
    for (; e < end; ++e) {
        const unsigned int* q = hu + (size_t)idx[e] * (H / 2) + lane * NW;
#pragma unroll
        for (int j = 0; j < NW; ++j) {
            unsigned int r = q[j];
            float f0 = bf2f(r & 0xffffu), f1 = bf2f(r >> 16);
            if constexpr (FUSE_BN) {
                f0 = fmaxf(f0 * sc[2 * j] + sh[2 * j], 0.f);
                f1 = fmaxf(f1 * sc[2 * j + 1] + sh[2 * j + 1], 0.f);
            }
            acc[2 * j] += f0;
            acc[2 * j + 1] += f1;
        }
    }
    unsigned int* op = (unsigned int*)out + (size_t)v * (H / 2) + lane * NW;
#pragma unroll
    for (int j = 0; j < NW; ++j)
        op[j] = (unsigned int)f2bf(acc[2 * j]) | ((unsigned int)f2bf(acc[2 * j + 1]) << 16);
}

// ---------------- bf16 MFMA GEMM, 128x256 tile, 512 threads / 8 waves -------
// (R9-proven shape + VGPR cap.) __launch_bounds__(512,4): 4 waves/EU -> VGPR
// <=128 -> 16 waves/CU -> 2 co-resident blocks/CU (LDS 2x52KB fits), so the
// 391-block grid runs in one round instead of 2 (1 block/CU at >128 VGPR).
// TRANS_A: A reg-staged with fused relu(x*sc+sh); sc/sh per-block from stats.
// Epilogue: +bias, write Y bf16, column stats via wm-pair LDS combine.
template<int K, bool TRANS_A>
__global__ __launch_bounds__(512, 4) void gemm_mfma(const unsigned short* __restrict__ A,
                                                 const unsigned short* __restrict__ Wt,
                                                 const float* __restrict__ bias,
                                                 const float* __restrict__ stats_in,
                                                 const float* __restrict__ gp,
                                                 const float* __restrict__ btp,
                                                 float invN,
                                                 unsigned short* __restrict__ Y,
                                                 float* __restrict__ stats_out,
                                                 int Nrows) {
    __shared__ unsigned short sA[2][128 * 32];   // [row][32k], 64B rows
    __shared__ unsigned short sB[2][256 * 32];   // [col][32k]
    __shared__ float reds[256], redq[256];
    __shared__ float spc[256], sps[256];
    const int tid = threadIdx.x;
    const int lane = tid & 63;
    const int wid = tid >> 6;          // 0..7
    const int wm = wid >> 2;           // 0..1 row-half
    const int wn = wid & 3;            // 0..3 col-quarter
    const int r0 = blockIdx.x * 128;
    const int arow = tid >> 2;         // 0..127
    const int akk = (tid & 3) * 8;     // bf16 k-offset

    if constexpr (TRANS_A) {
        if (tid < 256) {
            float m = stats_in[tid] * invN;
            float var = stats_in[256 + tid] * invN - m * m;
            float sv = gp[tid] * rsqrtf(var + 1e-5f);
            spc[tid] = sv;
            sps[tid] = btp[tid] - m * sv;
        }
        __syncthreads();
    }

    f32x4 acc[4][4] = {};

    auto stageB = [&](int buf, int k0) {
#pragma unroll
        for (int q = 0; q < 2; ++q) {
            int row = q * 128 + arow;   // 0..255 (col index of W^T)
            const unsigned short* gB = Wt + (size_t)row * K + k0 + akk;
            __builtin_amdgcn_global_load_lds(
                (const __attribute__((address_space(1))) void*)(uintptr_t)gB,
                (__attribute__((address_space(3))) void*)(uintptr_t)(&sB[buf][q * 4096 + tid * 8]),
                16, 0, 0);
        }
    };
    auto stageA_direct = [&](int buf, int k0) {
        const unsigned short* gA = A + (size_t)(r0 + arow) * K + k0 + akk;
        __builtin_amdgcn_global_load_lds(
            (const __attribute__((address_space(1))) void*)(uintptr_t)gA,
            (__attribute__((address_space(3))) void*)(uintptr_t)(&sA[buf][tid * 8]),
            16, 0, 0);
    };
    uint4 areg;
    auto loadA = [&](int k0) {
        areg = *(const uint4*)(A + (size_t)(r0 + arow) * K + k0 + akk);
    };
    auto writeA = [&](int buf, int k0) {
        float4 sca = *(const float4*)&spc[k0 + akk];
        float4 scb = *(const float4*)&spc[k0 + akk + 4];
        float4 sha = *(const float4*)&sps[k0 + akk];
        float4 shb = *(const float4*)&sps[k0 + akk + 4];
        uint4 u = areg;
        float f0 = fmaxf(bf2f(u.x & 0xffffu) * sca.x + sha.x, 0.f);
        float f1 = fmaxf(bf2f(u.x >> 16)     * sca.y + sha.y, 0.f);
        float f2 = fmaxf(bf2f(u.y & 0xffffu) * sca.z + sha.z, 0.f);
        float f3 = fmaxf(bf2f(u.y >> 16)     * sca.w + sha.w, 0.f);
        float f4 = fmaxf(bf2f(u.z & 0xffffu) * scb.x + shb.x, 0.f);
        float f5 = fmaxf(bf2f(u.z >> 16)     * scb.y + shb.y, 0.f);
        float f6 = fmaxf(bf2f(u.w & 0xffffu) * scb.z + shb.z, 0.f);
        float f7 = fmaxf(bf2f(u.w >> 16)     * scb.w + shb.w, 0.f);
        uint4 w;
        w.x = (unsigned int)f2bf(f0) | ((unsigned int)f2bf(f1) << 16);
        w.y = (unsigned int)f2bf(f2) | ((unsigned int)f2bf(f3) << 16);
        w.z = (unsigned int)f2bf(f4) | ((unsigned int)f2bf(f5) << 16);
        w.w = (unsigned int)f2bf(f6) | ((unsigned int)f2bf(f7) << 16);
        *(uint4*)&sA[buf][tid * 8] = w;
    };

    const int nt = K / 32;
    if constexpr (TRANS_A) { loadA(0); } else { stageA_direct(0, 0); }
    stageB(0, 0);
    const int krow = lane >> 4;
    const int rl = lane & 15;

    for (int t = 0; t < nt; ++t) {
        if constexpr (TRANS_A) writeA(t & 1, t * 32);
        __syncthreads();   // tile t fully in LDS (barrier drains vm+lgkm)
        if (t + 1 < nt) {
            stageB((t + 1) & 1, (t + 1) * 32);
            if constexpr (TRANS_A) loadA((t + 1) * 32);
            else stageA_direct((t + 1) & 1, (t + 1) * 32);
        }
        const unsigned short* sAb = sA[t & 1];
        const unsigned short* sBb = sB[t & 1];
        short8 a[4], b[4];
#pragma unroll
        for (int i = 0; i < 4; ++i) {
            a[i] = *(const short8*)(sAb + (wm * 64 + i * 16 + rl) * 32 + krow * 8);
            b[i] = *(const short8*)(sBb + (wn * 64 + i * 16 + rl) * 32 + krow * 8);
        }
#pragma unroll
        for (int i = 0; i < 4; ++i)
#pragma unroll
            for (int n = 0; n < 4; ++n)
                asm volatile("v_mfma_f32_16x16x32_bf16 %0, %1, %2, %0"
                             : "+v"(acc[i][n])
                             : "v"(a[i]), "v"(b[n]));
    }
    asm volatile("s_nop 7\n\ts_nop 7" ::);

    const int rg = lane >> 4;
    float ssum[4], qsum[4];
#pragma unroll
    for (int n = 0; n < 4; ++n) {
        int col = wn * 64 + n * 16 + rl;
        float bvv = bias[col];
        float s = 0.f, q2 = 0.f;
#pragma unroll
        for (int i = 0; i < 4; ++i) {
#pragma unroll
            for (int r = 0; r < 4; ++r) {
                int grow = r0 + wm * 64 + i * 16 + rg * 4 + r;
                if (grow < Nrows) {
                    float v = acc[i][n][r] + bvv;
                    Y[(size_t)grow * 256 + col] = f2bf(v);
                    s += v;
                    q2 += v * v;
                }
            }
        }
        s  += __shfl_xor(s, 16, 64);  s  += __shfl_xor(s, 32, 64);
        q2 += __shfl_xor(q2, 16, 64); q2 += __shfl_xor(q2, 32, 64);
        ssum[n] = s; qsum[n] = q2;
    }
    if (wm == 0 && rg == 0) {
#pragma unroll
        for (int n = 0; n < 4; ++n) {
            int lc = wn * 64 + n * 16 + rl;
            reds[lc] = ssum[n];
            redq[lc] = qsum[n];
        }
    }
    __syncthreads();
    if (wm == 1 && rg == 0) {
#pragma unroll
        for (int n = 0; n < 4; ++n) {
            int lc = wn * 64 + n * 16 + rl;
            atomicAdd(&stats_out[lc], ssum[n] + reds[lc]);
            atomicAdd(&stats_out[256 + lc], qsum[n] + redq[lc]);
        }
    }
}

// ---------------- final BN apply -> fp32 out ----------------
__global__ void bn_fuse(const unsigned short* __restrict__ Y, const float* __restrict__ stats,
                        const float* __restrict__ g, const float* __restrict__ bt,
                        float invN, float* __restrict__ outf, int total8) {
    int i = blockIdx.x * blockDim.x + threadIdx.x;
    if (i >= total8) return;
    int col0 = (i & 31) << 3;
    uint4 y = ((const uint4*)Y)[i];
    unsigned int yy[4] = {y.x, y.y, y.z, y.w};
    float o[8];
#pragma unroll
    for (int j = 0; j < 4; ++j) {
        o[2 * j]     = bf2f(yy[j] & 0xffffu);
        o[2 * j + 1] = bf2f(yy[j] >> 16);
    }
#pragma unroll
    for (int j = 0; j < 8; ++j) {
        int c = col0 + j;
        float mean = stats[c] * invN;
        float var = stats[256 + c] * invN - mean * mean;
        float sc = g[c] * rsqrtf(var + 1e-5f);
        float sh = bt[c] - mean * sc;
        o[j] = o[j] * sc + sh;
    }
    float4* of = (float4*)outf;
    of[2 * i]     = make_float4(o[0], o[1], o[2], o[3]);
    of[2 * i + 1] = make_float4(o[4], o[5], o[6], o[7]);
}

extern "C" void kernel_launch(void* const* d_in, const int* in_sizes, int n_in,
                              void* d_out, int out_size, void* d_ws, size_t ws_size,
                              hipStream_t stream) {
    const float* x      = (const float*)d_in[0];
    const int*   ei     = (const int*)d_in[1];
    const float* eps    = (const float*)d_in[2];
    const float* W1_0   = (const float*)d_in[3];
    const float* W1rest = (const float*)d_in[4];
    const float* b1     = (const float*)d_in[5];
    const float* g1     = (const float*)d_in[6];
    const float* bt1    = (const float*)d_in[7];
    const float* W2     = (const float*)d_in[8];
    const float* b2     = (const float*)d_in[9];
    const float* g2     = (const float*)d_in[10];
    const float* bt2    = (const float*)d_in[11];

    const int N = in_sizes[0] / 128;
    const int E = in_sizes[1] / 2;
    const int* row = ei;
    const int* col = ei + E;
    const int Npad = ((N + 127) / 128) * 128;
    const int nbRow = Npad / 128;

    char* w = (char*)d_ws;
    auto alloc = [&](size_t bytes) {
        char* p = w;
        w += (bytes + 255) & ~(size_t)255;
        return p;
    };
    unsigned short* xb = (unsigned short*)alloc((size_t)Npad * 128 * 2);
    unsigned short* p0 = (unsigned short*)alloc((size_t)Npad * 256 * 2);
    unsigned short* p1 = (unsigned short*)alloc((size_t)Npad * 256 * 2);
    unsigned short* Yb = (unsigned short*)alloc((size_t)Npad * 256 * 2);
    unsigned short* wt = (unsigned short*)alloc((size_t)360448 * 2);
    float* stats  = (float*)alloc(3072 * 4);
    int* deg    = (int*)alloc((size_t)N * 4);
    int* cursor = (int*)alloc((size_t)N * 4);
    int* rowptr = (int*)alloc((size_t)(N + 1) * 4);
    int* bs     = (int*)alloc(256 * 4);
    int* bo     = (int*)alloc(256 * 4);
    int* idxb   = (int*)alloc((size_t)E * 4);

    const float invN = 1.f / (float)N;
    const int B = (N + 255) / 256;

    // zero deg + buffer tails + stats (one launch, every call for graph replay)
    int tail16 = (Npad - N) * 256 * 2 / 16;
    {
        uint4* t0 = (uint4*)(p0 + (size_t)N * 256);
        uint4* t1 = (uint4*)(p1 + (size_t)N * 256);
        uint4* t2 = (uint4*)(Yb + (size_t)N * 256);
        int mx = N;
        if (tail16 > mx) mx = tail16;
        if (768 > mx) mx = 768;
        zero_all<<<(mx + 255) / 256, 256, 0, stream>>>(deg, N, t0, t1, t2, tail16,
                                                       (uint4*)stats, 768);
    }

    // conv + weight transpose + degree histogram (one launch)
    const int nconv = N * 32;
    {
        int total = nconv + 360448 + E;
        prep_all<<<(total + 255) / 256, 256, 0, stream>>>(x, xb, nconv,
                                                          W1_0, W1rest, W2, wt,
                                                          row, deg, E);
    }

    // CSR build
    block_sums<<<B, 256, 0, stream>>>(deg, bs, N);
    scan_bs<<<1, 256, 0, stream>>>(bs, bo, B);
    finalize_rowptr<<<B, 256, 0, stream>>>(deg, bo, rowptr, cursor, N, E);
    fill_csr<<<(E + 255) / 256, 256, 0, stream>>>(row, col, cursor, idxb, E);

    const int aggGrid = (N + 3) / 4;   // one wave per node
    const int bnGrid = (N * 32 + 255) / 256;

    for (int layer = 0; layer < 3; ++layer) {
        float* st1 = stats + layer * 1024;
        float* st2 = st1 + 512;
        float* st2p = stats + (layer - 1) * 1024 + 512;

        // aggregation -> p1 (layers 1,2: fused relu(bn2_prev(.)) on pre-BN p0)
        if (layer == 0)
            aggregate_f<128, false><<<aggGrid, 256, 0, stream>>>(
                xb, rowptr, idxb, eps, 0, nullptr, nullptr, nullptr, invN, p1, N);
        else
            aggregate_f<256, true><<<aggGrid, 256, 0, stream>>>(
                p0, rowptr, idxb, eps, layer, st2p,
                g2 + (layer - 1) * 256, bt2 + (layer - 1) * 256, invN, p1, N);

        // Linear1 + b1 + stats -> Yb (pre-BN1)
        if (layer == 0)
            gemm_mfma<128, false><<<nbRow, 512, 0, stream>>>(
                p1, wt, b1, nullptr, nullptr, nullptr, invN, Yb, st1, N);
        else
            gemm_mfma<256, false><<<nbRow, 512, 0, stream>>>(
                p1, wt + 32768 + (size_t)(layer - 1) * 65536, b1 + layer * 256,
                nullptr, nullptr, nullptr, invN, Yb, st1, N);

        // Linear2: A = relu(bn1(Yb)) fused in staging; + b2 + stats -> p0 (pre-BN2)
        gemm_mfma<256, true><<<nbRow, 512, 0, stream>>>(
            Yb, wt + 163840 + (size_t)layer * 65536, b2 + layer * 256,
            st1, g1 + layer * 256, bt1 + layer * 256, invN, p0, st2, N);
    }

    // final BN2 -> fp32 out
    bn_fuse<<<bnGrid, 256, 0, stream>>>(p0, stats + 2 * 1024 + 512,
                                        g2 + 2 * 256, bt2 + 2 * 256,
                                        invN, (float*)d_out, N * 32);
}

// Round 13
// 435.000 us; speedup vs baseline: 1.0042x; 1.0042x over previous
//
#include <hip/hip_runtime.h>
#include <hip/hip_bf16.h>
#include <math.h>
#include <stdint.h>

typedef short short8 __attribute__((ext_vector_type(8)));
typedef float f32x4 __attribute__((ext_vector_type(4)));

__device__ __forceinline__ float bf2f(unsigned int u) {
    union { unsigned int i; float f; } x; x.i = u << 16; return x.f;
}
__device__ __forceinline__ unsigned short f2bf(float f) {
    union { float f; unsigned int i; } x; x.f = f;
    unsigned int r = x.i + 0x7fffu + ((x.i >> 16) & 1u);
    return (unsigned short)(r >> 16);
}

// ---------------- CSR build ----------------
__global__ void block_sums(const int* __restrict__ deg, int* __restrict__ bs, int N) {
    __shared__ int tmp[256];
    int t = threadIdx.x;
    int i = blockIdx.x * 256 + t;
    tmp[t] = (i < N) ? deg[i] : 0;
    __syncthreads();
    for (int off = 128; off > 0; off >>= 1) {
        if (t < off) tmp[t] += tmp[t + off];
        __syncthreads();
    }
    if (t == 0) bs[blockIdx.x] = tmp[0];
}
__global__ void scan_bs(const int* __restrict__ bs, int* __restrict__ bo, int B) {
    __shared__ int tmp[256];
    int t = threadIdx.x;
    int v = (t < B) ? bs[t] : 0;
    tmp[t] = v;
    __syncthreads();
    for (int off = 1; off < 256; off <<= 1) {
        int x = (t >= off) ? tmp[t - off] : 0;
        __syncthreads();
        tmp[t] += x;
        __syncthreads();
    }
    bo[t] = tmp[t] - v;
}
__global__ void finalize_rowptr(const int* __restrict__ deg, const int* __restrict__ bo,
                                int* __restrict__ rowptr, int* __restrict__ cursor,
                                int N, int E) {
    __shared__ int tmp[256];
    int t = threadIdx.x;
    int i = blockIdx.x * 256 + t;
    int v = (i < N) ? deg[i] : 0;
    tmp[t] = v;
    __syncthreads();
    for (int off = 1; off < 256; off <<= 1) {
        int x = (t >= off) ? tmp[t - off] : 0;
        __syncthreads();
        tmp[t] += x;
        __syncthreads();
    }
    int excl = tmp[t] - v + bo[blockIdx.x];
    if (i < N) { rowptr[i] = excl; cursor[i] = excl; }
    if (i == N) rowptr[N] = E;
}
__global__ void fill_csr(const int* __restrict__ row, const int* __restrict__ col,
                         int* __restrict__ cursor, int* __restrict__ idx, int E) {
    int e = blockIdx.x * blockDim.x + threadIdx.x;
    if (e < E) {
        int p = atomicAdd(&cursor[row[e]], 1);
        idx[p] = col[e];
    }
}

// ---------------- merged zero + prep ----------------
__global__ void zero_all(int* __restrict__ deg, int n_deg,
                         uint4* __restrict__ a, uint4* __restrict__ b, uint4* __restrict__ c,
                         int n_t, uint4* __restrict__ st, int n_st) {
    int i = blockIdx.x * blockDim.x + threadIdx.x;
    uint4 z = make_uint4(0, 0, 0, 0);
    if (i < n_deg) deg[i] = 0;
    if (i < n_t) { a[i] = z; b[i] = z; c[i] = z; }
    if (i < n_st) st[i] = z;
}

// conv_x (nconv float4-items) + weight transpose/convert (360448) + degree hist (E)
__global__ void prep_all(const float* __restrict__ x, unsigned short* __restrict__ xb, int nconv,
                         const float* __restrict__ W1_0, const float* __restrict__ W1rest,
                         const float* __restrict__ W2, unsigned short* __restrict__ wt,
                         const int* __restrict__ erow, int* __restrict__ deg, int E) {
    int i = blockIdx.x * blockDim.x + threadIdx.x;
    if (i < nconv) {
        float4 v = *(const float4*)(x + (size_t)i * 4);
        unsigned int lo = (unsigned int)f2bf(v.x) | ((unsigned int)f2bf(v.y) << 16);
        unsigned int hi = (unsigned int)f2bf(v.z) | ((unsigned int)f2bf(v.w) << 16);
        *(uint2*)(xb + (size_t)i * 4) = make_uint2(lo, hi);
        return;
    }
    int id = i - nconv;
    if (id < 32768) {                       // W1_0 [128][256] -> [256][128]
        int k = id >> 8, c = id & 255;
        wt[c * 128 + k] = f2bf(W1_0[id]);
        return;
    } else if (id < 163840) {               // W1rest 2x [256][256]
        int t = id - 32768;
        int m = t >> 16, r = t & 65535;
        int k = r >> 8, c = r & 255;
        wt[32768 + m * 65536 + c * 256 + k] = f2bf(W1rest[t]);
        return;
    } else if (id < 360448) {               // W2 3x [256][256]
        int t = id - 163840;
        int m = t >> 16, r = t & 65535;
        int k = r >> 8, c = r & 255;
        wt[163840 + m * 65536 + c * 256 + k] = f2bf(W2[t]);
        return;
    }
    int e = id - 360448;
    if (e < E) atomicAdd(&deg[erow[e]], 1);
}

// ---------------- pull aggregation (R5-proven) + optional fused BN+ReLU -----
// out[v] = (1+eps)*T(h[v]) + sum_{u in N(v)} T(h[u]);  T = id or relu(x*sc+sh),
// sc/sh computed per-lane from column stats. One wave per node, 4-edge unroll.
template<int H, bool FUSE_BN>
__global__ __launch_bounds__(256) void aggregate_f(
    const unsigned short* __restrict__ h,
    const int* __restrict__ rowptr, const int* __restrict__ idx,
    const float* __restrict__ eps_p, int layer,
    const float* __restrict__ stats, const float* __restrict__ g,
    const float* __restrict__ bt, float invN,
    unsigned short* __restrict__ out, int N) {
    constexpr int NW = H / 128;  // uints (bf16 pairs) per lane
    int lane = threadIdx.x & 63;
    int v = blockIdx.x * 4 + (threadIdx.x >> 6);
    if (v >= N) return;

    float sc[2 * NW], sh[2 * NW];
    if constexpr (FUSE_BN) {
#pragma unroll
        for (int j = 0; j < 2 * NW; ++j) {
            int c = lane * 2 * NW + j;
            float m = stats[c] * invN;
            float var = stats[256 + c] * invN - m * m;
            sc[j] = g[c] * rsqrtf(var + 1e-5f);
            sh[j] = bt[c] - m * sc[j];
        }
    }
    const float s = 1.f + eps_p[layer];
    const unsigned int* hu = (const unsigned int*)h;

    float acc[2 * NW];
    {
        const unsigned int* hv = hu + (size_t)v * (H / 2) + lane * NW;
#pragma unroll
        for (int j = 0; j < NW; ++j) {
            unsigned int r = hv[j];
            float f0 = bf2f(r & 0xffffu), f1 = bf2f(r >> 16);
            if constexpr (FUSE_BN) {
                f0 = fmaxf(f0 * sc[2 * j] + sh[2 * j], 0.f);
                f1 = fmaxf(f1 * sc[2 * j + 1] + sh[2 * j + 1], 0.f);
            }
            acc[2 * j] = s * f0;
            acc[2 * j + 1] = s * f1;
        }
    }
    int e = rowptr[v], end = rowptr[v + 1];
    for (; e + 3 < end; e += 4) {
        int u0 = idx[e], u1 = idx[e + 1], u2 = idx[e + 2], u3 = idx[e + 3];
        const unsigned int* q0 = hu + (size_t)u0 * (H / 2) + lane * NW;
        const unsigned int* q1 = hu + (size_t)u1 * (H / 2) + lane * NW;
        const unsigned int* q2 = hu + (size_t)u2 * (H / 2) + lane * NW;
        const unsigned int* q3 = hu + (size_t)u3 * (H / 2) + lane * NW;
        unsigned int r0[NW], r1[NW], r2[NW], r3[NW];
#pragma unroll
        for (int j = 0; j < NW; ++j) { r0[j] = q0[j]; r1[j] = q1[j]; r2[j] = q2[j]; r3[j] = q3[j]; }
#pragma unroll
        for (int j = 0; j < NW; ++j) {
            float a0 = bf2f(r0[j] & 0xffffu), b0 = bf2f(r0[j] >> 16);
            float a1 = bf2f(r1[j] & 0xffffu), b1 = bf2f(r1[j] >> 16);
            float a2 = bf2f(r2[j] & 0xffffu), b2 = bf2f(r2[j] >> 16);
            float a3 = bf2f(r3[j] & 0xffffu), b3 = bf2f(r3[j] >> 16);
            if constexpr (FUSE_BN) {
                float c0 = sc[2 * j], d0 = sh[2 * j], c1 = sc[2 * j + 1], d1 = sh[2 * j + 1];
                a0 = fmaxf(a0 * c0 + d0, 0.f); b0 = fmaxf(b0 * c1 + d1, 0.f);
                a1 = fmaxf(a1 * c0 + d0, 0.f); b1 = fmaxf(b1 * c1 + d1, 0.f);
                a2 = fmaxf(a2 * c0 + d0, 0.f); b2 = fmaxf(b2 * c1 + d1, 0.f);
                a3 = fmaxf(a3 * c0 + d0, 0.f); b3 = fmaxf(b3 * c1 + d1, 0.f);
            }
            acc[2 * j]     += (a0 + a1) + (a2 + a3);
            acc[2 * j + 1] += (b0 + b1) + (b2 + b3);
        }
    }
    for (; e < end; ++e) {
        const unsigned int* q = hu + (size_t)idx[e] * (H / 2) + lane * NW;
#pragma unroll
        for (int j = 0; j < NW; ++j) {
            unsigned int r = q[j];
            float f0 = bf2f(r & 0xffffu), f1 = bf2f(r >> 16);
            if constexpr (FUSE_BN) {
                f0 = fmaxf(f0 * sc[2 * j] + sh[2 * j], 0.f);
                f1 = fmaxf(f1 * sc[2 * j + 1] + sh[2 * j + 1], 0.f);
            }
            acc[2 * j] += f0;
            acc[2 * j + 1] += f1;
        }
    }
    unsigned int* op = (unsigned int*)out + (size_t)v * (H / 2) + lane * NW;
#pragma unroll
    for (int j = 0; j < NW; ++j)
        op[j] = (unsigned int)f2bf(acc[2 * j]) | ((unsigned int)f2bf(acc[2 * j + 1]) << 16);
}

// ---------------- bf16 MFMA GEMM, 128x256 tile, 512 threads / 8 waves -------
// R13: LDS XOR-swizzle (T2). Rows are 64B (32 bf16) = 16 words -> unswizzled,
// the 16 lanes sharing krow land on banks {0,16}: 8-way conflict on every
// ds_read_b128. Swizzle: 16B chunk c of row r lives at slot c ^ ((r>>1)&3).
// global_load_lds writes linearly, so the permutation is applied on the
// GLOBAL source k-offset (rule #21) and on the read index; involution.
// Post-swizzle: 2-way (free). TRANS_A BN params indexed by the same swizzled
// akk so scale/shift match the loaded k-columns.
template<int K, bool TRANS_A>
__global__ __launch_bounds__(512, 4) void gemm_mfma(const unsigned short* __restrict__ A,
                                                 const unsigned short* __restrict__ Wt,
                                                 const float* __restrict__ bias,
                                                 const float* __restrict__ stats_in,
                                                 const float* __restrict__ gp,
                                                 const float* __restrict__ btp,
                                                 float invN,
                                                 unsigned short* __restrict__ Y,
                                                 float* __restrict__ stats_out,
                                                 int Nrows) {
    __shared__ unsigned short sA[2][128 * 32];   // [row][32k], 64B rows, k-chunks swizzled
    __shared__ unsigned short sB[2][256 * 32];   // [col][32k], k-chunks swizzled
    __shared__ float reds[256], redq[256];
    __shared__ float spc[256], sps[256];
    const int tid = threadIdx.x;
    const int lane = tid & 63;
    const int wid = tid >> 6;          // 0..7
    const int wm = wid >> 2;           // 0..1 row-half
    const int wn = wid & 3;            // 0..3 col-quarter
    const int r0 = blockIdx.x * 128;
    const int arow = tid >> 2;         // 0..127 (LDS row this thread stages)
    // swizzled source chunk: LDS slot (tid&3) of row arow holds global chunk
    // (tid&3) ^ ((arow>>1)&3)
    const int akk = (((tid & 3) ^ ((tid >> 3) & 3))) * 8;   // bf16 k-offset (swizzled)

    if constexpr (TRANS_A) {
        if (tid < 256) {
            float m = stats_in[tid] * invN;
            float var = stats_in[256 + tid] * invN - m * m;
            float sv = gp[tid] * rsqrtf(var + 1e-5f);
            spc[tid] = sv;
            sps[tid] = btp[tid] - m * sv;
        }
        __syncthreads();
    }

    f32x4 acc[4][4] = {};

    auto stageB = [&](int buf, int k0) {
#pragma unroll
        for (int q = 0; q < 2; ++q) {
            int row = q * 128 + arow;   // 0..255 (col index of W^T); (row>>1)&3 == (arow>>1)&3
            const unsigned short* gB = Wt + (size_t)row * K + k0 + akk;
            __builtin_amdgcn_global_load_lds(
                (const __attribute__((address_space(1))) void*)(uintptr_t)gB,
                (__attribute__((address_space(3))) void*)(uintptr_t)(&sB[buf][q * 4096 + tid * 8]),
                16, 0, 0);
        }
    };
    auto stageA_direct = [&](int buf, int k0) {
        const unsigned short* gA = A + (size_t)(r0 + arow) * K + k0 + akk;
        __builtin_amdgcn_global_load_lds(
            (const __attribute__((address_space(1))) void*)(uintptr_t)gA,
            (__attribute__((address_space(3))) void*)(uintptr_t)(&sA[buf][tid * 8]),
            16, 0, 0);
    };
    uint4 areg;
    auto loadA = [&](int k0) {
        areg = *(const uint4*)(A + (size_t)(r0 + arow) * K + k0 + akk);
    };
    auto writeA = [&](int buf, int k0) {
        float4 sca = *(const float4*)&spc[k0 + akk];
        float4 scb = *(const float4*)&spc[k0 + akk + 4];
        float4 sha = *(const float4*)&sps[k0 + akk];
        float4 shb = *(const float4*)&sps[k0 + akk + 4];
        uint4 u = areg;
        float f0 = fmaxf(bf2f(u.x & 0xffffu) * sca.x + sha.x, 0.f);
        float f1 = fmaxf(bf2f(u.x >> 16)     * sca.y + sha.y, 0.f);
        float f2 = fmaxf(bf2f(u.y & 0xffffu) * sca.z + sha.z, 0.f);
        float f3 = fmaxf(bf2f(u.y >> 16)     * sca.w + sha.w, 0.f);
        float f4 = fmaxf(bf2f(u.z & 0xffffu) * scb.x + shb.x, 0.f);
        float f5 = fmaxf(bf2f(u.z >> 16)     * scb.y + shb.y, 0.f);
        float f6 = fmaxf(bf2f(u.w & 0xffffu) * scb.z + shb.z, 0.f);
        float f7 = fmaxf(bf2f(u.w >> 16)     * scb.w + shb.w, 0.f);
        uint4 w;
        w.x = (unsigned int)f2bf(f0) | ((unsigned int)f2bf(f1) << 16);
        w.y = (unsigned int)f2bf(f2) | ((unsigned int)f2bf(f3) << 16);
        w.z = (unsigned int)f2bf(f4) | ((unsigned int)f2bf(f5) << 16);
        w.w = (unsigned int)f2bf(f6) | ((unsigned int)f2bf(f7) << 16);
        *(uint4*)&sA[buf][tid * 8] = w;
    };

    const int nt = K / 32;
    if constexpr (TRANS_A) { loadA(0); } else { stageA_direct(0, 0); }
    stageB(0, 0);
    const int krow = lane >> 4;
    const int rl = lane & 15;
    const int ksw = (rl >> 1) & 3;     // read-side chunk swizzle for this lane's rows

    for (int t = 0; t < nt; ++t) {
        if constexpr (TRANS_A) writeA(t & 1, t * 32);
        __syncthreads();   // tile t fully in LDS (barrier drains vm+lgkm)
        if (t + 1 < nt) {
            stageB((t + 1) & 1, (t + 1) * 32);
            if constexpr (TRANS_A) loadA((t + 1) * 32);
            else stageA_direct((t + 1) & 1, (t + 1) * 32);
        }
        const unsigned short* sAb = sA[t & 1];
        const unsigned short* sBb = sB[t & 1];
        short8 a[4], b[4];
#pragma unroll
        for (int i = 0; i < 4; ++i) {
            // row = wm*64+i*16+rl; (row>>1)&3 == (rl>>1)&3 since i*16,wm*64 = 0 mod 8
            a[i] = *(const short8*)(sAb + (wm * 64 + i * 16 + rl) * 32 + (krow ^ ksw) * 8);
            b[i] = *(const short8*)(sBb + (wn * 64 + i * 16 + rl) * 32 + (krow ^ ksw) * 8);
        }
#pragma unroll
        for (int i = 0; i < 4; ++i)
#pragma unroll
            for (int n = 0; n < 4; ++n)
                asm volatile("v_mfma_f32_16x16x32_bf16 %0, %1, %2, %0"
                             : "+v"(acc[i][n])
                             : "v"(a[i]), "v"(b[n]));
    }
    asm volatile("s_nop 7\n\ts_nop 7" ::);

    const int rg = lane >> 4;
    float ssum[4], qsum[4];
#pragma unroll
    for (int n = 0; n < 4; ++n) {
        int col = wn * 64 + n * 16 + rl;
        float bvv = bias[col];
        float s = 0.f, q2 = 0.f;
#pragma unroll
        for (int i = 0; i < 4; ++i) {
#pragma unroll
            for (int r = 0; r < 4; ++r) {
                int grow = r0 + wm * 64 + i * 16 + rg * 4 + r;
                if (grow < Nrows) {
                    float v = acc[i][n][r] + bvv;
                    Y[(size_t)grow * 256 + col] = f2bf(v);
                    s += v;
                    q2 += v * v;
                }
            }
        }
        s  += __shfl_xor(s, 16, 64);  s  += __shfl_xor(s, 32, 64);
        q2 += __shfl_xor(q2, 16, 64); q2 += __shfl_xor(q2, 32, 64);
        ssum[n] = s; qsum[n] = q2;
    }
    if (wm == 0 && rg == 0) {
#pragma unroll
        for (int n = 0; n < 4; ++n) {
            int lc = wn * 64 + n * 16 + rl;
            reds[lc] = ssum[n];
            redq[lc] = qsum[n];
        }
    }
    __syncthreads();
    if (wm == 1 && rg == 0) {
#pragma unroll
        for (int n = 0; n < 4; ++n) {
            int lc = wn * 64 + n * 16 + rl;
            atomicAdd(&stats_out[lc], ssum[n] + reds[lc]);
            atomicAdd(&stats_out[256 + lc], qsum[n] + redq[lc]);
        }
    }
}

// ---------------- final BN apply -> fp32 out ----------------
__global__ void bn_fuse(const unsigned short* __restrict__ Y, const float* __restrict__ stats,
                        const float* __restrict__ g, const float* __restrict__ bt,
                        float invN, float* __restrict__ outf, int total8) {
    int i = blockIdx.x * blockDim.x + threadIdx.x;
    if (i >= total8) return;
    int col0 = (i & 31) << 3;
    uint4 y = ((const uint4*)Y)[i];
    unsigned int yy[4] = {y.x, y.y, y.z, y.w};
    float o[8];
#pragma unroll
    for (int j = 0; j < 4; ++j) {
        o[2 * j]     = bf2f(yy[j] & 0xffffu);
        o[2 * j + 1] = bf2f(yy[j] >> 16);
    }
#pragma unroll
    for (int j = 0; j < 8; ++j) {
        int c = col0 + j;
        float mean = stats[c] * invN;
        float var = stats[256 + c] * invN - mean * mean;
        float sc = g[c] * rsqrtf(var + 1e-5f);
        float sh = bt[c] - mean * sc;
        o[j] = o[j] * sc + sh;
    }
    float4* of = (float4*)outf;
    of[2 * i]     = make_float4(o[0], o[1], o[2], o[3]);
    of[2 * i + 1] = make_float4(o[4], o[5], o[6], o[7]);
}

extern "C" void kernel_launch(void* const* d_in, const int* in_sizes, int n_in,
                              void* d_out, int out_size, void* d_ws, size_t ws_size,
                              hipStream_t stream) {
    const float* x      = (const float*)d_in[0];
    const int*   ei     = (const int*)d_in[1];
    const float* eps    = (const float*)d_in[2];
    const float* W1_0   = (const float*)d_in[3];
    const float* W1rest = (const float*)d_in[4];
    const float* b1     = (const float*)d_in[5];
    const float* g1     = (const float*)d_in[6];
    const float* bt1    = (const float*)d_in[7];
    const float* W2     = (const float*)d_in[8];
    const float* b2     = (const float*)d_in[9];
    const float* g2     = (const float*)d_in[10];
    const float* bt2    = (const float*)d_in[11];

    const int N = in_sizes[0] / 128;
    const int E = in_sizes[1] / 2;
    const int* row = ei;
    const int* col = ei + E;
    const int Npad = ((N + 127) / 128) * 128;
    const int nbRow = Npad / 128;

    char* w = (char*)d_ws;
    auto alloc = [&](size_t bytes) {
        char* p = w;
        w += (bytes + 255) & ~(size_t)255;
        return p;
    };
    unsigned short* xb = (unsigned short*)alloc((size_t)Npad * 128 * 2);
    unsigned short* p0 = (unsigned short*)alloc((size_t)Npad * 256 * 2);
    unsigned short* p1 = (unsigned short*)alloc((size_t)Npad * 256 * 2);
    unsigned short* Yb = (unsigned short*)alloc((size_t)Npad * 256 * 2);
    unsigned short* wt = (unsigned short*)alloc((size_t)360448 * 2);
    float* stats  = (float*)alloc(3072 * 4);
    int* deg    = (int*)alloc((size_t)N * 4);
    int* cursor = (int*)alloc((size_t)N * 4);
    int* rowptr = (int*)alloc((size_t)(N + 1) * 4);
    int* bs     = (int*)alloc(256 * 4);
    int* bo     = (int*)alloc(256 * 4);
    int* idxb   = (int*)alloc((size_t)E * 4);

    const float invN = 1.f / (float)N;
    const int B = (N + 255) / 256;

    // zero deg + buffer tails + stats (one launch, every call for graph replay)
    int tail16 = (Npad - N) * 256 * 2 / 16;
    {
        uint4* t0 = (uint4*)(p0 + (size_t)N * 256);
        uint4* t1 = (uint4*)(p1 + (size_t)N * 256);
        uint4* t2 = (uint4*)(Yb + (size_t)N * 256);
        int mx = N;
        if (tail16 > mx) mx = tail16;
        if (768 > mx) mx = 768;
        zero_all<<<(mx + 255) / 256, 256, 0, stream>>>(deg, N, t0, t1, t2, tail16,
                                                       (uint4*)stats, 768);
    }

    // conv + weight transpose + degree histogram (one launch)
    const int nconv = N * 32;
    {
        int total = nconv + 360448 + E;
        prep_all<<<(total + 255) / 256, 256, 0, stream>>>(x, xb, nconv,
                                                          W1_0, W1rest, W2, wt,
                                                          row, deg, E);
    }

    // CSR build
    block_sums<<<B, 256, 0, stream>>>(deg, bs, N);
    scan_bs<<<1, 256, 0, stream>>>(bs, bo, B);
    finalize_rowptr<<<B, 256, 0, stream>>>(deg, bo, rowptr, cursor, N, E);
    fill_csr<<<(E + 255) / 256, 256, 0, stream>>>(row, col, cursor, idxb, E);

    const int aggGrid = (N + 3) / 4;   // one wave per node
    const int bnGrid = (N * 32 + 255) / 256;

    for (int layer = 0; layer < 3; ++layer) {
        float* st1 = stats + layer * 1024;
        float* st2 = st1 + 512;
        float* st2p = stats + (layer - 1) * 1024 + 512;

        // aggregation -> p1 (layers 1,2: fused relu(bn2_prev(.)) on pre-BN p0)
        if (layer == 0)
            aggregate_f<128, false><<<aggGrid, 256, 0, stream>>>(
                xb, rowptr, idxb, eps, 0, nullptr, nullptr, nullptr, invN, p1, N);
        else
            aggregate_f<256, true><<<aggGrid, 256, 0, stream>>>(
                p0, rowptr, idxb, eps, layer, st2p,
                g2 + (layer - 1) * 256, bt2 + (layer - 1) * 256, invN, p1, N);

        // Linear1 + b1 + stats -> Yb (pre-BN1)
        if (layer == 0)
            gemm_mfma<128, false><<<nbRow, 512, 0, stream>>>(
                p1, wt, b1, nullptr, nullptr, nullptr, invN, Yb, st1, N);
        else
            gemm_mfma<256, false><<<nbRow, 512, 0, stream>>>(
                p1, wt + 32768 + (size_t)(layer - 1) * 65536, b1 + layer * 256,
                nullptr, nullptr, nullptr, invN, Yb, st1, N);

        // Linear2: A = relu(bn1(Yb)) fused in staging; + b2 + stats -> p0 (pre-BN2)
        gemm_mfma<256, true><<<nbRow, 512, 0, stream>>>(
            Yb, wt + 163840 + (size_t)layer * 65536, b2 + layer * 256,
            st1, g1 + layer * 256, bt1 + layer * 256, invN, p0, st2, N);
    }

    // final BN2 -> fp32 out
    bn_fuse<<<bnGrid, 256, 0, stream>>>(p0, stats + 2 * 1024 + 512,
                                        g2 + 2 * 256, bt2 + 2 * 256,
                                        invN, (float*)d_out, N * 32);
}